// Round 5
// baseline (96.461 us; speedup 1.0000x reference)
//
#include <hip/hip_runtime.h>

// DeformableDETR loss. B=1024, Q=900, C=8, Nt=32.
// R4: per-class onehot logic removed — all 8 classes use the uniform
//     non-target focal p^2*softplus(x); matched queries (3.5%) get a single
//     EXEC-masked correction for the target class (scalar L1 reload).
//     Class table packs ((t+1)<<8)|lbl with background=8 -> tgt = &0xFF.
//     900/512 loop unrolled to explicit 2-query form, loads front-loaded.
// R3 lesson kept: per-image float4 partials via plain stores (R2's same-line
// device atomics cost +52 us); tiny finalize kernel applies weights.

constexpr int Bc  = 1024;
constexpr int Qc  = 900;
constexpr int Cc  = 8;
constexpr int NTc = 32;
constexpr int NTHR = 512;

__device__ inline float wave_reduce(float v) {
#pragma unroll
    for (int o = 32; o > 0; o >>= 1) v += __shfl_down(v, o, 64);
    return v;
}

// Non-target focal core: p^2 * softplus(x), p = sigmoid(x). Also folds x into mx.
__device__ inline float focal_nt(float x, float& mx) {
    mx      = fmaxf(mx, x);
    float e = __expf(-fabsf(x));
    float t = 1.f + e;
    float r = 1.f / t;                 // sigmoid(|x|)
    float L = __logf(t);               // log1p(exp(-|x|))
    float p = (x >= 0.f) ? r : (1.f - r);   // sigmoid(x)
    float sp = L + fmaxf(x, 0.f);           // softplus(x)
    return p * p * sp;
}

// Replace target class's non-target term with its true focal term.
__device__ inline float corr_tgt(float x) {
    float e = __expf(-fabsf(x));
    float t = 1.f + e;
    float r = 1.f / t;
    float L = __logf(t);
    float p   = (x >= 0.f) ? r : (1.f - r);
    float q_  = 1.f - p;               // sigmoid(-x)
    float spx = L + fmaxf(x, 0.f);     // softplus(x)
    float spn = spx - x;               // softplus(-x)
    return 0.25f * q_ * q_ * spn - 0.75f * p * p * spx;
}

__device__ inline float query_ce(const float* __restrict__ basep, int q, int tgt,
                                 const float* __restrict__ s_ew, float& card) {
    const float4* lp = (const float4*)(basep + (size_t)q * Cc);
    float4 xa = lp[0], xb = lp[1];
    float mx = -1e30f;
    float fs = focal_nt(xa.x, mx) + focal_nt(xa.y, mx) +
               focal_nt(xa.z, mx) + focal_nt(xa.w, mx) +
               focal_nt(xb.x, mx) + focal_nt(xb.y, mx) +
               focal_nt(xb.z, mx) + focal_nt(xb.w, mx);
    float base = 0.75f * fs;
    if (tgt < Cc) {                    // matched query: rare, EXEC-masked
        float xt = basep[(size_t)q * Cc + tgt];   // L1-hot reload
        base += corr_tgt(xt);
    }
    card += (mx > 0.f) ? 1.f : 0.f;    // sigmoid(max)>0.5 <=> max>0
    return base * s_ew[tgt];
}

__global__ __launch_bounds__(NTHR) void detr_partial(
    const float* __restrict__ logits,   // [B,Q,C]
    const float* __restrict__ pboxes,   // [B,Q,4] cxcywh
    const float* __restrict__ tboxes,   // [B,Nt,4] cxcywh
    const int*   __restrict__ sidx,     // [B,Nt]
    const int*   __restrict__ tlbl,     // [B,Nt]
    const float* __restrict__ ew,       // [C+1]
    float4*      __restrict__ partials) // [B] {ce, bbox, giou, |card-Nt|}
{
    const int b   = blockIdx.x;
    const int tid = threadIdx.x;

    __shared__ int   s_cls[Qc];        // ((t+1)<<8)|lbl, background = Cc
    __shared__ int   s_src[NTc];
    __shared__ int   s_lbl[NTc];
    __shared__ float s_ew[Cc + 1];
    __shared__ float s_red[8][4];

    s_cls[tid] = Cc;
    if (tid < Qc - NTHR) s_cls[tid + NTHR] = Cc;
    if (tid < NTc) {
        s_src[tid] = sidx[b * NTc + tid];
        s_lbl[tid] = tlbl[b * NTc + tid];
    }
    if (tid < Cc + 1) s_ew[tid] = ew[tid];
    __syncthreads();
    // max over (t+1) == last-wins numpy scatter; all packed values > Cc
    if (tid < NTc) atomicMax(&s_cls[s_src[tid]], ((tid + 1) << 8) | s_lbl[tid]);
    __syncthreads();

    // ---- focal CE + cardinality: q1 = tid (always valid), q2 = tid+512 ----
    const float* basep = logits + (size_t)b * Qc * Cc;
    const int q1 = tid, q2 = tid + NTHR;
    const bool has2 = (q2 < Qc);
    const int tgt1 = s_cls[q1] & 0xFF;
    const int tgt2 = has2 ? (s_cls[q2] & 0xFF) : 0;

    float ce = 0.f, card = 0.f;
    ce += query_ce(basep, q1, tgt1, s_ew, card);
    if (has2) ce += query_ce(basep, q2, tgt2, s_ew, card);

    // ---- matched-box L1 + GIoU (threads 0..31, one per target) ----
    float lbb = 0.f, lgi = 0.f;
    if (tid < NTc) {
        int q = s_src[tid], lab = s_lbl[tid];
        float4 sb = *(const float4*)(pboxes + ((size_t)(b * Qc + q)) * 4);
        float4 tb = *(const float4*)(tboxes + ((size_t)(b * NTc + tid)) * 4);
        float scale = (lab == 4 || lab == 5 || lab == 6) ? 2.f : 1.f;

        lbb = (fabsf(sb.x - tb.x) + fabsf(sb.y - tb.y) +
               fabsf(sb.z - tb.z) + fabsf(sb.w - tb.w)) * scale;

        float ax0 = sb.x - 0.5f * sb.z, ay0 = sb.y - 0.5f * sb.w;
        float ax1 = sb.x + 0.5f * sb.z, ay1 = sb.y + 0.5f * sb.w;
        float bx0 = tb.x - 0.5f * tb.z, by0 = tb.y - 0.5f * tb.w;
        float bx1 = tb.x + 0.5f * tb.z, by1 = tb.y + 0.5f * tb.w;

        float areaA = (ax1 - ax0) * (ay1 - ay0);
        float areaB = (bx1 - bx0) * (by1 - by0);
        float iw = fmaxf(fminf(ax1, bx1) - fmaxf(ax0, bx0), 0.f);
        float ih = fmaxf(fminf(ay1, by1) - fmaxf(ay0, by0), 0.f);
        float inter = iw * ih;
        float uni   = areaA + areaB - inter;
        float iou   = inter / uni;
        float ewd = fmaxf(fmaxf(ax1, bx1) - fminf(ax0, bx0), 0.f);
        float ehd = fmaxf(fmaxf(ay1, by1) - fminf(ay0, by0), 0.f);
        float areaE = ewd * ehd;
        float g = iou - (areaE - uni) / areaE;
        lgi = (1.f - g) * scale;
    }

    // ---- block reduce {ce, lbb, lgi, card} across 8 waves ----
    float vals[4] = {ce, lbb, lgi, card};
    const int lane = tid & 63, wave = tid >> 6;
#pragma unroll
    for (int k = 0; k < 4; ++k) {
        float v = wave_reduce(vals[k]);
        if (lane == 0) s_red[wave][k] = v;
    }
    __syncthreads();
    if (tid == 0) {
        float s[4];
#pragma unroll
        for (int k = 0; k < 4; ++k) {
            float a = 0.f;
#pragma unroll
            for (int w = 0; w < 8; ++w) a += s_red[w][k];
            s[k] = a;
        }
        float4 r;
        r.x = s[0];
        r.y = s[1];
        r.z = s[2];
        r.w = fabsf(s[3] - (float)NTc);   // per-image |card - Nt|
        partials[b] = r;
    }
}

__global__ __launch_bounds__(256) void detr_finalize(
    const float4* __restrict__ partials, float* __restrict__ out)
{
    const int tid = threadIdx.x;
    __shared__ float s_red[4][4];

    float4 a = {0.f, 0.f, 0.f, 0.f};
    for (int i = tid; i < Bc; i += 256) {
        float4 p = partials[i];
        a.x += p.x; a.y += p.y; a.z += p.z; a.w += p.w;
    }
    float vals[4] = {a.x, a.y, a.z, a.w};
    const int lane = tid & 63, wave = tid >> 6;
#pragma unroll
    for (int k = 0; k < 4; ++k) {
        float v = wave_reduce(vals[k]);
        if (lane == 0) s_red[wave][k] = v;
    }
    __syncthreads();
    if (tid == 0) {
        float ce   = s_red[0][0] + s_red[1][0] + s_red[2][0] + s_red[3][0];
        float bbox = s_red[0][1] + s_red[1][1] + s_red[2][1] + s_red[3][1];
        float giou = s_red[0][2] + s_red[1][2] + s_red[2][2] + s_red[3][2];
        float card = s_red[0][3] + s_red[1][3] + s_red[2][3] + s_red[3][3];
        const float nb = (float)(Bc * NTc) + 1e-8f;   // num_boxes
        out[0] = 1.0f * ce   / nb;          // W_CE
        out[1] = 5.0f * bbox / nb;          // W_BBOX
        out[2] = 2.0f * giou / nb;          // W_GIOU
        out[3] = 1.0f * card / (float)Bc;   // W_CARD, mean over images
    }
}

extern "C" void kernel_launch(void* const* d_in, const int* in_sizes, int n_in,
                              void* d_out, int out_size, void* d_ws, size_t ws_size,
                              hipStream_t stream) {
    const float* logits = (const float*)d_in[0];
    const float* pboxes = (const float*)d_in[1];
    const float* tboxes = (const float*)d_in[2];
    const int*   sidx   = (const int*)d_in[3];
    const int*   tlbl   = (const int*)d_in[4];
    const float* ew     = (const float*)d_in[5];
    float4* partials = (float4*)d_ws;   // 1024 * 16 B = 16 KiB

    detr_partial<<<Bc, NTHR, 0, stream>>>(logits, pboxes, tboxes, sidx, tlbl, ew, partials);
    detr_finalize<<<1, 256, 0, stream>>>(partials, (float*)d_out);
}

// Round 6
// 95.430 us; speedup vs baseline: 1.0108x; 1.0108x over previous
//
#include <hip/hip_runtime.h>

// DeformableDETR loss. B=1024, Q=900, C=8, Nt=32.
// R5: R3 structure (plain-store per-image partials + finalize kernel; R2's
//     same-line device atomics cost +52us, R4's divergent target-correction
//     branch cost +1.4us — both reverted). Focal math reformulated on u=e^x
//     (inputs fixed N(0,1), |x|<6, no overflow):
//       t=1+u, r=1/t, L=log t  =>  softplus(x)=L, softplus(-x)=L-x,
//       p=u*r, 1-p=r.
//       non-target: 0.75*(u*r)^2*L     target: 0.25*r^2*(L-x)
//     selected per class by 3 uniform cndmasks — no divergence, no fabs,
//     no sigmoid sign-select: ~10 VALU + 3 trans per class (was ~13+3).
// Class lookup: LDS table, atomicMax on ((t+1)<<8)|lbl, background=Cc;
// max over t == numpy last-wins scatter.

constexpr int Bc  = 1024;
constexpr int Qc  = 900;
constexpr int Cc  = 8;
constexpr int NTc = 32;
constexpr int NTHR = 512;

__device__ inline float wave_reduce(float v) {
#pragma unroll
    for (int o = 32; o > 0; o >>= 1) v += __shfl_down(v, o, 64);
    return v;
}

// Focal term for one class. oh = (c == tgt). mx accumulates max logit.
__device__ inline float focal1(float x, bool oh, float& mx) {
    mx      = fmaxf(mx, x);
    float u = __expf(x);          // e^x, safe for |x|<88
    float t = 1.f + u;
    float r = 1.f / t;            // = 1-p
    float L = __logf(t);          // = softplus(x)
    float s1 = oh ? 1.f  : u;
    float s2 = oh ? (L - x) : L;  // softplus(-x) = L - x
    float cf = oh ? 0.25f : 0.75f;
    float m  = s1 * r;            // oh ? (1-p) : p
    return cf * (m * m) * s2;
}

__global__ __launch_bounds__(NTHR) void detr_partial(
    const float* __restrict__ logits,   // [B,Q,C]
    const float* __restrict__ pboxes,   // [B,Q,4] cxcywh
    const float* __restrict__ tboxes,   // [B,Nt,4] cxcywh
    const int*   __restrict__ sidx,     // [B,Nt]
    const int*   __restrict__ tlbl,     // [B,Nt]
    const float* __restrict__ ew,       // [C+1]
    float4*      __restrict__ partials) // [B] {ce, bbox, giou, |card-Nt|}
{
    const int b   = blockIdx.x;
    const int tid = threadIdx.x;

    __shared__ int   s_cls[Qc];        // ((t+1)<<8)|lbl, background = Cc
    __shared__ int   s_src[NTc];
    __shared__ int   s_lbl[NTc];
    __shared__ float s_ew[Cc + 1];
    __shared__ float s_red[8][4];

    s_cls[tid] = Cc;
    if (tid < Qc - NTHR) s_cls[tid + NTHR] = Cc;
    if (tid < NTc) {
        s_src[tid] = sidx[b * NTc + tid];
        s_lbl[tid] = tlbl[b * NTc + tid];
    }
    if (tid < Cc + 1) s_ew[tid] = ew[tid];
    __syncthreads();
    // max over (t+1) == last-wins numpy scatter; all packed values > Cc
    if (tid < NTc) atomicMax(&s_cls[s_src[tid]], ((tid + 1) << 8) | s_lbl[tid]);
    __syncthreads();

    // ---- focal CE + cardinality: q1 = tid (always valid), q2 = tid+512 ----
    const float* basep = logits + (size_t)b * Qc * Cc;
    const int q1 = tid, q2 = tid + NTHR;
    const bool has2 = (q2 < Qc);

    float ce = 0.f, card = 0.f;
    {
        const int tgt = s_cls[q1] & 0xFF;
        const float4* lp = (const float4*)(basep + (size_t)q1 * Cc);
        float4 xa = lp[0], xb = lp[1];
        float mx = -1e30f;
        float fs = focal1(xa.x, tgt == 0, mx) + focal1(xa.y, tgt == 1, mx) +
                   focal1(xa.z, tgt == 2, mx) + focal1(xa.w, tgt == 3, mx) +
                   focal1(xb.x, tgt == 4, mx) + focal1(xb.y, tgt == 5, mx) +
                   focal1(xb.z, tgt == 6, mx) + focal1(xb.w, tgt == 7, mx);
        ce   += fs * s_ew[tgt];
        card += (mx > 0.f) ? 1.f : 0.f;   // sigmoid(max)>0.5 <=> max>0
    }
    if (has2) {
        const int tgt = s_cls[q2] & 0xFF;
        const float4* lp = (const float4*)(basep + (size_t)q2 * Cc);
        float4 xa = lp[0], xb = lp[1];
        float mx = -1e30f;
        float fs = focal1(xa.x, tgt == 0, mx) + focal1(xa.y, tgt == 1, mx) +
                   focal1(xa.z, tgt == 2, mx) + focal1(xa.w, tgt == 3, mx) +
                   focal1(xb.x, tgt == 4, mx) + focal1(xb.y, tgt == 5, mx) +
                   focal1(xb.z, tgt == 6, mx) + focal1(xb.w, tgt == 7, mx);
        ce   += fs * s_ew[tgt];
        card += (mx > 0.f) ? 1.f : 0.f;
    }

    // ---- matched-box L1 + GIoU (threads 0..31, one per target) ----
    float lbb = 0.f, lgi = 0.f;
    if (tid < NTc) {
        int q = s_src[tid], lab = s_lbl[tid];
        float4 sb = *(const float4*)(pboxes + ((size_t)(b * Qc + q)) * 4);
        float4 tb = *(const float4*)(tboxes + ((size_t)(b * NTc + tid)) * 4);
        float scale = (lab == 4 || lab == 5 || lab == 6) ? 2.f : 1.f;

        lbb = (fabsf(sb.x - tb.x) + fabsf(sb.y - tb.y) +
               fabsf(sb.z - tb.z) + fabsf(sb.w - tb.w)) * scale;

        float ax0 = sb.x - 0.5f * sb.z, ay0 = sb.y - 0.5f * sb.w;
        float ax1 = sb.x + 0.5f * sb.z, ay1 = sb.y + 0.5f * sb.w;
        float bx0 = tb.x - 0.5f * tb.z, by0 = tb.y - 0.5f * tb.w;
        float bx1 = tb.x + 0.5f * tb.z, by1 = tb.y + 0.5f * tb.w;

        float areaA = (ax1 - ax0) * (ay1 - ay0);
        float areaB = (bx1 - bx0) * (by1 - by0);
        float iw = fmaxf(fminf(ax1, bx1) - fmaxf(ax0, bx0), 0.f);
        float ih = fmaxf(fminf(ay1, by1) - fmaxf(ay0, by0), 0.f);
        float inter = iw * ih;
        float uni   = areaA + areaB - inter;
        float iou   = inter / uni;
        float ewd = fmaxf(fmaxf(ax1, bx1) - fminf(ax0, bx0), 0.f);
        float ehd = fmaxf(fmaxf(ay1, by1) - fminf(ay0, by0), 0.f);
        float areaE = ewd * ehd;
        float g = iou - (areaE - uni) / areaE;
        lgi = (1.f - g) * scale;
    }

    // ---- block reduce {ce, lbb, lgi, card} across 8 waves ----
    float vals[4] = {ce, lbb, lgi, card};
    const int lane = tid & 63, wave = tid >> 6;
#pragma unroll
    for (int k = 0; k < 4; ++k) {
        float v = wave_reduce(vals[k]);
        if (lane == 0) s_red[wave][k] = v;
    }
    __syncthreads();
    if (tid == 0) {
        float s[4];
#pragma unroll
        for (int k = 0; k < 4; ++k) {
            float a = 0.f;
#pragma unroll
            for (int w = 0; w < 8; ++w) a += s_red[w][k];
            s[k] = a;
        }
        float4 r;
        r.x = s[0];
        r.y = s[1];
        r.z = s[2];
        r.w = fabsf(s[3] - (float)NTc);   // per-image |card - Nt|
        partials[b] = r;
    }
}

__global__ __launch_bounds__(256) void detr_finalize(
    const float4* __restrict__ partials, float* __restrict__ out)
{
    const int tid = threadIdx.x;
    __shared__ float s_red[4][4];

    float4 a = {0.f, 0.f, 0.f, 0.f};
    for (int i = tid; i < Bc; i += 256) {
        float4 p = partials[i];
        a.x += p.x; a.y += p.y; a.z += p.z; a.w += p.w;
    }
    float vals[4] = {a.x, a.y, a.z, a.w};
    const int lane = tid & 63, wave = tid >> 6;
#pragma unroll
    for (int k = 0; k < 4; ++k) {
        float v = wave_reduce(vals[k]);
        if (lane == 0) s_red[wave][k] = v;
    }
    __syncthreads();
    if (tid == 0) {
        float ce   = s_red[0][0] + s_red[1][0] + s_red[2][0] + s_red[3][0];
        float bbox = s_red[0][1] + s_red[1][1] + s_red[2][1] + s_red[3][1];
        float giou = s_red[0][2] + s_red[1][2] + s_red[2][2] + s_red[3][2];
        float card = s_red[0][3] + s_red[1][3] + s_red[2][3] + s_red[3][3];
        const float nb = (float)(Bc * NTc) + 1e-8f;   // num_boxes
        out[0] = 1.0f * ce   / nb;          // W_CE
        out[1] = 5.0f * bbox / nb;          // W_BBOX
        out[2] = 2.0f * giou / nb;          // W_GIOU
        out[3] = 1.0f * card / (float)Bc;   // W_CARD, mean over images
    }
}

extern "C" void kernel_launch(void* const* d_in, const int* in_sizes, int n_in,
                              void* d_out, int out_size, void* d_ws, size_t ws_size,
                              hipStream_t stream) {
    const float* logits = (const float*)d_in[0];
    const float* pboxes = (const float*)d_in[1];
    const float* tboxes = (const float*)d_in[2];
    const int*   sidx   = (const int*)d_in[3];
    const int*   tlbl   = (const int*)d_in[4];
    const float* ew     = (const float*)d_in[5];
    float4* partials = (float4*)d_ws;   // 1024 * 16 B = 16 KiB

    detr_partial<<<Bc, NTHR, 0, stream>>>(logits, pboxes, tboxes, sidx, tlbl, ew, partials);
    detr_finalize<<<1, 256, 0, stream>>>(partials, (float*)d_out);
}

// Round 7
// 93.279 us; speedup vs baseline: 1.0341x; 1.0231x over previous
//
#include <hip/hip_runtime.h>

// DeformableDETR loss. B=1024, Q=900, C=8, Nt=32.
// R6: two changes over R5:
//  (1) 1.f/t replaced by __builtin_amdgcn_rcpf — harness has no -ffast-math,
//      so "/" lowered to the full IEEE div sequence (~8-10 instrs incl.
//      quarter-rate div_fmas) x16 per thread = the hidden VALU elephant.
//  (2) both queries' float4 loads issued unconditionally up front
//      (q2 aliases q1 for tid>=388, contribution gated) — 4 loads in flight
//      instead of load-compute-load-compute.
// Structure unchanged from R3/R5: plain-store per-image float4 partials
// (R2's same-line device atomics cost +52us), LDS class table via atomicMax
// on ((t+1)<<8)|lbl (== numpy last-wins scatter), finalize kernel applies
// weights. Focal on u=e^x: t=1+u, r=rcp(t), L=log t; softplus(x)=L,
// softplus(-x)=L-x, p=u*r, 1-p=r.

constexpr int Bc  = 1024;
constexpr int Qc  = 900;
constexpr int Cc  = 8;
constexpr int NTc = 32;
constexpr int NTHR = 512;

__device__ inline float wave_reduce(float v) {
#pragma unroll
    for (int o = 32; o > 0; o >>= 1) v += __shfl_down(v, o, 64);
    return v;
}

// Focal term for one class. oh = (c == tgt). mx accumulates max logit.
__device__ inline float focal1(float x, bool oh, float& mx) {
    mx      = fmaxf(mx, x);
    float u = __expf(x);                    // e^x, |x|<6 here
    float t = 1.f + u;
    float r = __builtin_amdgcn_rcpf(t);     // = 1-p   (fast rcp, 1 instr)
    float L = __logf(t);                    // = softplus(x)
    float s1 = oh ? 1.f  : u;
    float s2 = oh ? (L - x) : L;            // softplus(-x) = L - x
    float cf = oh ? 0.25f : 0.75f;
    float m  = s1 * r;                      // oh ? (1-p) : p
    return cf * (m * m) * s2;
}

__device__ inline float query_focal(float4 xa, float4 xb, int tgt, float& card) {
    float mx = -1e30f;
    float fs = focal1(xa.x, tgt == 0, mx) + focal1(xa.y, tgt == 1, mx) +
               focal1(xa.z, tgt == 2, mx) + focal1(xa.w, tgt == 3, mx) +
               focal1(xb.x, tgt == 4, mx) + focal1(xb.y, tgt == 5, mx) +
               focal1(xb.z, tgt == 6, mx) + focal1(xb.w, tgt == 7, mx);
    card += (mx > 0.f) ? 1.f : 0.f;         // sigmoid(max)>0.5 <=> max>0
    return fs;
}

__global__ __launch_bounds__(NTHR) void detr_partial(
    const float* __restrict__ logits,   // [B,Q,C]
    const float* __restrict__ pboxes,   // [B,Q,4] cxcywh
    const float* __restrict__ tboxes,   // [B,Nt,4] cxcywh
    const int*   __restrict__ sidx,     // [B,Nt]
    const int*   __restrict__ tlbl,     // [B,Nt]
    const float* __restrict__ ew,       // [C+1]
    float4*      __restrict__ partials) // [B] {ce, bbox, giou, |card-Nt|}
{
    const int b   = blockIdx.x;
    const int tid = threadIdx.x;

    __shared__ int   s_cls[Qc];        // ((t+1)<<8)|lbl, background = Cc
    __shared__ int   s_src[NTc];
    __shared__ int   s_lbl[NTc];
    __shared__ float s_ew[Cc + 1];
    __shared__ float s_red[8][4];

    s_cls[tid] = Cc;
    if (tid < Qc - NTHR) s_cls[tid + NTHR] = Cc;
    if (tid < NTc) {
        s_src[tid] = sidx[b * NTc + tid];
        s_lbl[tid] = tlbl[b * NTc + tid];
    }
    if (tid < Cc + 1) s_ew[tid] = ew[tid];
    __syncthreads();
    // max over (t+1) == last-wins numpy scatter; all packed values > Cc
    if (tid < NTc) atomicMax(&s_cls[s_src[tid]], ((tid + 1) << 8) | s_lbl[tid]);
    __syncthreads();

    // ---- focal CE + cardinality: q1 = tid, q2 = tid+512 (alias q1 if absent)
    const float* basep = logits + (size_t)b * Qc * Cc;
    const bool has2 = (tid + NTHR < Qc);
    const int q1 = tid;
    const int q2 = has2 ? (tid + NTHR) : tid;

    // issue all four 16B loads before any compute
    const float4* lp1 = (const float4*)(basep + (size_t)q1 * Cc);
    const float4* lp2 = (const float4*)(basep + (size_t)q2 * Cc);
    float4 a1 = lp1[0], b1 = lp1[1];
    float4 a2 = lp2[0], b2 = lp2[1];
    const int tgt1 = s_cls[q1] & 0xFF;
    const int tgt2 = s_cls[q2] & 0xFF;

    float ce = 0.f, card = 0.f;
    ce += query_focal(a1, b1, tgt1, card) * s_ew[tgt1];
    float card2 = 0.f;
    float fs2 = query_focal(a2, b2, tgt2, card2) * s_ew[tgt2];
    if (has2) { ce += fs2; card += card2; }

    // ---- matched-box L1 + GIoU (threads 0..31, one per target) ----
    float lbb = 0.f, lgi = 0.f;
    if (tid < NTc) {
        int q = s_src[tid], lab = s_lbl[tid];
        float4 sb = *(const float4*)(pboxes + ((size_t)(b * Qc + q)) * 4);
        float4 tb = *(const float4*)(tboxes + ((size_t)(b * NTc + tid)) * 4);
        float scale = (lab == 4 || lab == 5 || lab == 6) ? 2.f : 1.f;

        lbb = (fabsf(sb.x - tb.x) + fabsf(sb.y - tb.y) +
               fabsf(sb.z - tb.z) + fabsf(sb.w - tb.w)) * scale;

        float ax0 = sb.x - 0.5f * sb.z, ay0 = sb.y - 0.5f * sb.w;
        float ax1 = sb.x + 0.5f * sb.z, ay1 = sb.y + 0.5f * sb.w;
        float bx0 = tb.x - 0.5f * tb.z, by0 = tb.y - 0.5f * tb.w;
        float bx1 = tb.x + 0.5f * tb.z, by1 = tb.y + 0.5f * tb.w;

        float areaA = (ax1 - ax0) * (ay1 - ay0);
        float areaB = (bx1 - bx0) * (by1 - by0);
        float iw = fmaxf(fminf(ax1, bx1) - fmaxf(ax0, bx0), 0.f);
        float ih = fmaxf(fminf(ay1, by1) - fmaxf(ay0, by0), 0.f);
        float inter = iw * ih;
        float uni   = areaA + areaB - inter;
        float iou   = inter * __builtin_amdgcn_rcpf(uni);
        float ewd = fmaxf(fmaxf(ax1, bx1) - fminf(ax0, bx0), 0.f);
        float ehd = fmaxf(fmaxf(ay1, by1) - fminf(ay0, by0), 0.f);
        float areaE = ewd * ehd;
        float g = iou - (areaE - uni) * __builtin_amdgcn_rcpf(areaE);
        lgi = (1.f - g) * scale;
    }

    // ---- block reduce {ce, lbb, lgi, card} across 8 waves ----
    float vals[4] = {ce, lbb, lgi, card};
    const int lane = tid & 63, wave = tid >> 6;
#pragma unroll
    for (int k = 0; k < 4; ++k) {
        float v = wave_reduce(vals[k]);
        if (lane == 0) s_red[wave][k] = v;
    }
    __syncthreads();
    if (tid == 0) {
        float s[4];
#pragma unroll
        for (int k = 0; k < 4; ++k) {
            float a = 0.f;
#pragma unroll
            for (int w = 0; w < 8; ++w) a += s_red[w][k];
            s[k] = a;
        }
        float4 r;
        r.x = s[0];
        r.y = s[1];
        r.z = s[2];
        r.w = fabsf(s[3] - (float)NTc);   // per-image |card - Nt|
        partials[b] = r;
    }
}

__global__ __launch_bounds__(256) void detr_finalize(
    const float4* __restrict__ partials, float* __restrict__ out)
{
    const int tid = threadIdx.x;
    __shared__ float s_red[4][4];

    float4 a = {0.f, 0.f, 0.f, 0.f};
    for (int i = tid; i < Bc; i += 256) {
        float4 p = partials[i];
        a.x += p.x; a.y += p.y; a.z += p.z; a.w += p.w;
    }
    float vals[4] = {a.x, a.y, a.z, a.w};
    const int lane = tid & 63, wave = tid >> 6;
#pragma unroll
    for (int k = 0; k < 4; ++k) {
        float v = wave_reduce(vals[k]);
        if (lane == 0) s_red[wave][k] = v;
    }
    __syncthreads();
    if (tid == 0) {
        float ce   = s_red[0][0] + s_red[1][0] + s_red[2][0] + s_red[3][0];
        float bbox = s_red[0][1] + s_red[1][1] + s_red[2][1] + s_red[3][1];
        float giou = s_red[0][2] + s_red[1][2] + s_red[2][2] + s_red[3][2];
        float card = s_red[0][3] + s_red[1][3] + s_red[2][3] + s_red[3][3];
        const float nb = (float)(Bc * NTc) + 1e-8f;   // num_boxes
        out[0] = 1.0f * ce   / nb;          // W_CE
        out[1] = 5.0f * bbox / nb;          // W_BBOX
        out[2] = 2.0f * giou / nb;          // W_GIOU
        out[3] = 1.0f * card / (float)Bc;   // W_CARD, mean over images
    }
}

extern "C" void kernel_launch(void* const* d_in, const int* in_sizes, int n_in,
                              void* d_out, int out_size, void* d_ws, size_t ws_size,
                              hipStream_t stream) {
    const float* logits = (const float*)d_in[0];
    const float* pboxes = (const float*)d_in[1];
    const float* tboxes = (const float*)d_in[2];
    const int*   sidx   = (const int*)d_in[3];
    const int*   tlbl   = (const int*)d_in[4];
    const float* ew     = (const float*)d_in[5];
    float4* partials = (float4*)d_ws;   // 1024 * 16 B = 16 KiB

    detr_partial<<<Bc, NTHR, 0, stream>>>(logits, pboxes, tboxes, sidx, tlbl, ew, partials);
    detr_finalize<<<1, 256, 0, stream>>>(partials, (float*)d_out);
}